// Round 7
// baseline (246.668 us; speedup 1.0000x reference)
//
#include <hip/hip_runtime.h>

// LIF scan over T=16: mem_t = beta*mem + x_t - spk_{t-1}; spk_t = (mem_t - 1) > 0.
// One thread owns 4 neurons (float4) per group, 2 groups per thread.
// R7: rolling software pipeline. History: R1/R3/R4 compiler re-sunk register
// prefetch (straight-line code -> loads moved to uses, ~2 in flight); R6's
// LDS-DMA burst was real but decayed 16->0 with no refill (same avg depth).
// Fix: prefetch group i+1's load t in the SAME slot v[t] right after consuming
// group i's — uses are in the NEXT loop iteration, so the scheduler cannot
// sink them (no straight-line distance to collapse). Constant ~16-op vmem
// window sustained for the whole kernel: 16 waves/CU x 16 KB ~ 190 KB/CU
// outstanding (vs ~40 KB in R1/R6).

constexpr int   T      = 16;
constexpr float BETA   = 0.9f;
constexpr float THRESH = 1.0f;

typedef float f4 __attribute__((ext_vector_type(4)));

__global__ __launch_bounds__(256, 4) void lif_kernel(const float* __restrict__ x,
                                                     float* __restrict__ out,
                                                     int n_per_t) {
    // No FMA contraction: must match numpy's two-rounding fp32 exactly, else
    // ~1-ulp drift flips spikes at the threshold (absmax = 1.0 cascades).
#pragma clang fp contract(off)
    const int tid      = blockIdx.x * blockDim.x + threadIdx.x;
    const int nthreads = gridDim.x * blockDim.x;

    const size_t np   = (size_t)n_per_t;
    const size_t step = (size_t)nthreads * 4;
    size_t       idx  = (size_t)tid * 4;
    if (idx >= np) return;

    f4 v[T];  // rotating load buffer: 64 VGPRs, intentionally live

    // Prologue: burst group 0's 16 loads (coalesced 1 KB/wave each).
#pragma unroll
    for (int t = 0; t < T; ++t) {
        v[t] = *reinterpret_cast<const f4*>(x + (size_t)t * np + idx);
    }

    // Steady loop: consume v[t], refill v[t] with next group's load t, store.
    // Runtime trip count (depends on gridDim) keeps this a real loop.
#pragma clang loop unroll(disable)
    for (;;) {
        const size_t nidx = idx + step;
        const bool   more = nidx < np;

        f4 mem = (f4)(0.f);
        f4 spk = (f4)(0.f);
#pragma unroll
        for (int t = 0; t < T; ++t) {
            const f4 xt = v[t];
            if (more) {  // prefetch next group's load t into the freed slot
                v[t] = *reinterpret_cast<const f4*>(x + (size_t)t * np + nidx);
            }
#pragma unroll
            for (int j = 0; j < 4; ++j) {
                mem[j] = BETA * mem[j] + xt[j] - spk[j] * THRESH;
                spk[j] = (mem[j] - THRESH) > 0.f ? 1.f : 0.f;
            }
            __builtin_nontemporal_store(spk,
                reinterpret_cast<f4*>(out + (size_t)t * np + idx));
        }

        if (!more) break;
        idx = nidx;
    }
}

extern "C" void kernel_launch(void* const* d_in, const int* in_sizes, int n_in,
                              void* d_out, int out_size, void* d_ws, size_t ws_size,
                              hipStream_t stream) {
    const float* x   = (const float*)d_in[0];
    float*       out = (float*)d_out;

    const int total   = in_sizes[0];      // 33,554,432
    const int n_per_t = total / T;        // 2,097,152
    const int groups  = n_per_t / 4;      // 524,288 float4 groups
    const int gpt     = 2;                // groups per thread (pipeline depth amortization)
    const int threads = groups / gpt;     // 262,144
    dim3 block(256);
    dim3 grid(threads / block.x);         // 1024 blocks -> 4 blocks/CU, 16 waves/CU
    lif_kernel<<<grid, block, 0, stream>>>(x, out, n_per_t);
}